// Round 3
// baseline (449.624 us; speedup 1.0000x reference)
//
#include <hip/hip_runtime.h>

// Problem constants
constexpr int Bn = 32, Tn = 8, Cn = 1024, Sn = 4096, Hn = 16, HDn = 64;
constexpr int NCHUNK = 16;      // 4096 / 256 keys per chunk-block
constexpr int KSPLIT = 4;       // K-split for the 256x1024x1024 GEMMs
constexpr float SCALE = 0.125f; // 1/sqrt(64)

// Workspace layout (in floats)
constexpr size_t PROJ_PART = (size_t)Bn * Tn * Cn;          // 262144 (one partial)
constexpr size_t QP_OFF = 0;
constexpr size_t KP_OFF = QP_OFF + KSPLIT * PROJ_PART;
constexpr size_t VP_OFF = KP_OFF + KSPLIT * PROJ_PART;
constexpr size_t PACC_OFF = VP_OFF + KSPLIT * PROJ_PART;
constexpr size_t PACC_SZ = (size_t)NCHUNK * Bn * Hn * Tn * HDn;
constexpr size_t PL_OFF = PACC_OFF + PACC_SZ;
constexpr size_t PL_SZ = (size_t)NCHUNK * Bn * Hn * Tn;
constexpr size_t AW_OFF = PL_OFF + PL_SZ;
constexpr size_t AW_SZ = (size_t)Bn * Tn * Cn;
constexpr size_t OP_OFF = AW_OFF + AW_SZ;
constexpr size_t OP_SZ = (size_t)KSPLIT * PROJ_PART;
constexpr size_t QR_OFF = OP_OFF + OP_SZ;                   // reduced q (pre-scaled)
constexpr size_t KN_OFF = QR_OFF + PROJ_PART;               // reduced k_new
constexpr size_t VN_OFF = KN_OFF + PROJ_PART;               // reduced v_new

typedef __attribute__((address_space(3))) unsigned int lds_uint;
typedef const __attribute__((address_space(1))) unsigned int glb_uint;

__device__ __forceinline__ void gload_lds16(const float* g, float* l) {
    __builtin_amdgcn_global_load_lds((glb_uint*)g, (lds_uint*)l, 16, 0, 0);
}

// ---------------- GEMM: Y_partial[sigma] = X(256xK-slice) @ W^T ----------------
__device__ __forceinline__ void gemm_body(const float* __restrict__ X,
                                          const float* __restrict__ W,
                                          float* __restrict__ Opart,
                                          int sigma, int jblk, int iblk) {
    __shared__ float wl[64][68]; // [k][j], pad 68
    const int tid = threadIdx.x;
    const int c = tid & 15, a = tid >> 4;
    const int j0 = jblk * 64;
    const int ib = iblk * 64 + a * 4;
    const int k0 = sigma * 256;

    float acc[4][4];
#pragma unroll
    for (int ii = 0; ii < 4; ++ii)
#pragma unroll
        for (int jj = 0; jj < 4; ++jj) acc[ii][jj] = 0.f;

    for (int kt = 0; kt < 4; ++kt) {
        const int k1 = k0 + kt * 64;
#pragma unroll
        for (int stp = 0; stp < 4; ++stp) {
            int f4 = stp * 256 + tid;
            int jr = f4 >> 4, e4 = f4 & 15;
            float4 wv = *(const float4*)&W[(size_t)(j0 + jr) * Cn + k1 + e4 * 4];
            wl[e4 * 4 + 0][jr] = wv.x;
            wl[e4 * 4 + 1][jr] = wv.y;
            wl[e4 * 4 + 2][jr] = wv.z;
            wl[e4 * 4 + 3][jr] = wv.w;
        }
        __syncthreads();
#pragma unroll 4
        for (int k4 = 0; k4 < 16; ++k4) {
            float4 xv[4];
#pragma unroll
            for (int ii = 0; ii < 4; ++ii)
                xv[ii] = *(const float4*)&X[(size_t)(ib + ii) * Cn + k1 + k4 * 4];
#pragma unroll
            for (int kk = 0; kk < 4; ++kk) {
                float4 wv = *(const float4*)&wl[k4 * 4 + kk][c * 4];
#pragma unroll
                for (int ii = 0; ii < 4; ++ii) {
                    const float xs = (kk == 0) ? xv[ii].x : (kk == 1) ? xv[ii].y
                                   : (kk == 2) ? xv[ii].z : xv[ii].w;
                    acc[ii][0] += xs * wv.x;
                    acc[ii][1] += xs * wv.y;
                    acc[ii][2] += xs * wv.z;
                    acc[ii][3] += xs * wv.w;
                }
            }
        }
        __syncthreads();
    }
    float* op = Opart + (size_t)sigma * PROJ_PART;
#pragma unroll
    for (int ii = 0; ii < 4; ++ii) {
        float4 o = make_float4(acc[ii][0], acc[ii][1], acc[ii][2], acc[ii][3]);
        *(float4*)&op[(size_t)(ib + ii) * Cn + j0 + c * 4] = o;
    }
}

__global__ __launch_bounds__(256) void proj3_kernel(
    const float* __restrict__ X, const float* __restrict__ W0,
    const float* __restrict__ W1, const float* __restrict__ W2,
    float* __restrict__ O0, float* __restrict__ O1, float* __restrict__ O2) {
    const int z = blockIdx.z;
    const float* W = (z < 4) ? W0 : (z < 8 ? W1 : W2);
    float* O = (z < 4) ? O0 : (z < 8 ? O1 : O2);
    gemm_body(X, W, O, z & 3, blockIdx.x, blockIdx.y);
}

__global__ __launch_bounds__(256) void gemm1_kernel(
    const float* __restrict__ X, const float* __restrict__ W, float* __restrict__ O) {
    gemm_body(X, W, O, blockIdx.z, blockIdx.x, blockIdx.y);
}

// ---------------- Pre-reduce K-split partials -> q (scaled), k_new, v_new ------
__global__ __launch_bounds__(256) void prereduce_kernel(
    const float* __restrict__ qp, const float* __restrict__ kp,
    const float* __restrict__ vp, float* __restrict__ q,
    float* __restrict__ kn, float* __restrict__ vn) {
    const size_t i = ((size_t)blockIdx.x * 256 + threadIdx.x) * 4;
#define SUM4(P)                                                              \
    make_float4(                                                             \
        (*(const float4*)(P + i)).x + (*(const float4*)(P + PROJ_PART + i)).x + \
        (*(const float4*)(P + 2 * PROJ_PART + i)).x + (*(const float4*)(P + 3 * PROJ_PART + i)).x, \
        (*(const float4*)(P + i)).y + (*(const float4*)(P + PROJ_PART + i)).y + \
        (*(const float4*)(P + 2 * PROJ_PART + i)).y + (*(const float4*)(P + 3 * PROJ_PART + i)).y, \
        (*(const float4*)(P + i)).z + (*(const float4*)(P + PROJ_PART + i)).z + \
        (*(const float4*)(P + 2 * PROJ_PART + i)).z + (*(const float4*)(P + 3 * PROJ_PART + i)).z, \
        (*(const float4*)(P + i)).w + (*(const float4*)(P + PROJ_PART + i)).w + \
        (*(const float4*)(P + 2 * PROJ_PART + i)).w + (*(const float4*)(P + 3 * PROJ_PART + i)).w)
    float4 qv = SUM4(qp);
    qv.x *= SCALE; qv.y *= SCALE; qv.z *= SCALE; qv.w *= SCALE;
    *(float4*)&q[i] = qv;
    *(float4*)&kn[i] = SUM4(kp);
    *(float4*)&vn[i] = SUM4(vp);
#undef SUM4
}

// ---------------- Attention partials ----------------
// Grid (cq=16, h=16, b=32), block 256 = 4 independent waves, 64 key rows each.
// Per wave: 32 outstanding global_load_lds_dwordx4 (K swizzled-source + V linear),
// counted vmcnt(16) -> QK overlaps V stream, vmcnt(0) -> PV. No shfl in hot path.
__global__ __launch_bounds__(256) void attn_kernel(
    const float* __restrict__ q, const float* __restrict__ kn,
    const float* __restrict__ vn, const float* __restrict__ ck,
    const float* __restrict__ cv, const int* __restrict__ clen,
    float* __restrict__ pacc, float* __restrict__ pl) {
    const int cq = blockIdx.x, h = blockIdx.y, b = blockIdx.z;
    const int cl = clen[b];
    if (!(cq == 0 || cq * 256 < cl)) return; // uniform early exit

    const int tid = threadIdx.x, wave = tid >> 6, lane = tid & 63;

    __shared__ float K_l[4][64][64]; // 64 KB, per-wave, XOR-swizzled slots
    __shared__ float V_l[4][64][64]; // 64 KB, per-wave, linear
    __shared__ float q_l[4][8][64];  // 8 KB, per-wave private (no barrier)
    __shared__ float p_l[4][8][64];  // 8 KB, [t][row]; reused as reduce buffer
    __shared__ float p2_l[8][8];     // new-key p [t][row]
    __shared__ float redl[4][8];

    // max(cache_len) early (retire this load before the gload_lds cluster)
    int mv = clen[lane & 31];
#pragma unroll
    for (int off = 16; off >= 1; off >>= 1) {
        int o = __shfl_xor(mv, off);
        mv = mv > o ? mv : o;
    }

    // stage q (pre-scaled) into this wave's private q_l copy
    {
        const float* qb = q + (size_t)b * Tn * Cn + h * HDn;
#pragma unroll
        for (int r = 0; r < 2; ++r) {
            int f4 = r * 64 + lane; // 0..127
            int t = f4 >> 4, e4 = f4 & 15;
            float4 v = *(const float4*)(qb + (size_t)t * Cn + e4 * 4);
            *(float4*)&q_l[wave][t][e4 * 4] = v;
        }
    }
    __builtin_amdgcn_sched_barrier(0);

    const int r0 = cq * 256 + wave * 64;
    const int row_in = lane >> 4; // 0..3
    const int slot = lane & 15;
    const size_t gbase = ((size_t)b * Sn + r0) * Cn + (size_t)h * HDn;

    // issue 16 K gload_lds (swizzled global source -> linear LDS = swizzled slots)
#pragma unroll
    for (int i = 0; i < 16; ++i) {
        const int row = i * 4 + row_in;
        const int dg = slot ^ (row & 7);
        gload_lds16(ck + gbase + (size_t)row * Cn + dg * 4, &K_l[wave][i * 4][0]);
    }
    __builtin_amdgcn_sched_barrier(0);
    // issue 16 V gload_lds (linear)
#pragma unroll
    for (int i = 0; i < 16; ++i) {
        const int row = i * 4 + row_in;
        gload_lds16(cv + gbase + (size_t)row * Cn + slot * 4, &V_l[wave][i * 4][0]);
    }
    __builtin_amdgcn_sched_barrier(0);

    int n_valid = cl - r0;
    n_valid = n_valid < 0 ? 0 : (n_valid > 64 ? 64 : n_valid);

    // wait K resident (16 V remain in flight)
    asm volatile("s_waitcnt vmcnt(16)" ::: "memory");
    __builtin_amdgcn_sched_barrier(0);

    // QK: lane = row; swizzled conflict-free b128 reads
    float s[8];
#pragma unroll
    for (int t = 0; t < 8; ++t) s[t] = 0.f;
    const int swz = lane & 7;
#pragma unroll
    for (int dg = 0; dg < 16; ++dg) {
        float4 kv = *(const float4*)&K_l[wave][lane][(dg ^ swz) * 4];
#pragma unroll
        for (int t = 0; t < 8; ++t) {
            float4 qv = *(const float4*)&q_l[wave][t][dg * 4];
            s[t] += kv.x * qv.x + kv.y * qv.y + kv.z * qv.z + kv.w * qv.w;
        }
    }
    const bool val = lane < n_valid;
    float lden[8];
#pragma unroll
    for (int t = 0; t < 8; ++t) {
        float p = val ? __expf(s[t]) : 0.f;
        lden[t] = p;
        p_l[wave][t][lane] = p; // bank = lane%32, 2-way = free
    }

    // wait V resident
    asm volatile("s_waitcnt vmcnt(0)" ::: "memory");
    __builtin_amdgcn_sched_barrier(0);

    // PV: lane = d
    float av[8];
#pragma unroll
    for (int t = 0; t < 8; ++t) av[t] = 0.f;
#pragma unroll 4
    for (int s4 = 0; s4 < 16; ++s4) {
        float4 pt[8];
#pragma unroll
        for (int t = 0; t < 8; ++t) pt[t] = *(const float4*)&p_l[wave][t][s4 * 4];
        float vr[4];
#pragma unroll
        for (int u = 0; u < 4; ++u) vr[u] = V_l[wave][s4 * 4 + u][lane];
#pragma unroll
        for (int u = 0; u < 4; ++u) {
#pragma unroll
            for (int t = 0; t < 8; ++t) {
                const float pu = (u == 0) ? pt[t].x : (u == 1) ? pt[t].y
                               : (u == 2) ? pt[t].z : pt[t].w;
                av[t] += pu * vr[u];
            }
        }
    }

    // new keys (8 rows) + zero-pad denominator: wave 0 of chunk 0 only
    if (wave == 0 && cq == 0) {
        const int pad = mv - cl;
        const int row = lane >> 3, d0 = (lane & 7) * 8;
        const float* kb = kn + ((size_t)b * Tn + row) * Cn + h * HDn + d0;
        float4 k0 = *(const float4*)(kb);
        float4 k1 = *(const float4*)(kb + 4);
        float sn[8];
#pragma unroll
        for (int t = 0; t < 8; ++t) {
            const float4 q0 = *(const float4*)&q_l[0][t][d0];
            const float4 q1 = *(const float4*)&q_l[0][t][d0 + 4];
            float v = k0.x * q0.x + k0.y * q0.y + k0.z * q0.z + k0.w * q0.w +
                      k1.x * q1.x + k1.y * q1.y + k1.z * q1.z + k1.w * q1.w;
            v += __shfl_xor(v, 1);
            v += __shfl_xor(v, 2);
            v += __shfl_xor(v, 4);
            sn[t] = __expf(v);
        }
        if ((lane & 7) == 0) {
#pragma unroll
            for (int t = 0; t < 8; ++t) {
                lden[t] += sn[t];
                p2_l[t][row] = sn[t];
            }
        }
        if (lane == 0) {
#pragma unroll
            for (int t = 0; t < 8; ++t) lden[t] += (float)pad;
        }
        // PV over new keys: lane = d
#pragma unroll
        for (int r = 0; r < 8; ++r) {
            const float v = vn[((size_t)b * Tn + r) * Cn + h * HDn + lane];
#pragma unroll
            for (int t = 0; t < 8; ++t) av[t] += p2_l[t][r] * v;
        }
    }

    // lden: per-wave 64-lane butterfly (each row counted once)
#pragma unroll
    for (int t = 0; t < 8; ++t) {
        float v = lden[t];
#pragma unroll
        for (int off = 32; off >= 1; off >>= 1) v += __shfl_xor(v, off);
        lden[t] = v;
    }
    if (lane == 0) {
#pragma unroll
        for (int t = 0; t < 8; ++t) redl[wave][t] = lden[t];
    }
    // av into reduce buffer (reuse p_l: per-wave region, own wave done with it)
#pragma unroll
    for (int t = 0; t < 8; ++t) p_l[wave][t][lane] = av[t];

    __syncthreads();
    const size_t obase = (size_t)((cq * Bn + b) * Hn + h);
#pragma unroll
    for (int rep = 0; rep < 2; ++rep) {
        int e = rep * 256 + tid;
        int t = e >> 6, d = e & 63;
        float sum = p_l[0][t][d] + p_l[1][t][d] + p_l[2][t][d] + p_l[3][t][d];
        pacc[obase * 512 + e] = sum;
    }
    if (tid < 8) pl[obase * 8 + tid] = redl[0][tid] + redl[1][tid] + redl[2][tid] + redl[3][tid];
}

// ---------------- Merge chunk partials, normalize ----------------
__global__ __launch_bounds__(64) void attn_merge_kernel(
    const float* __restrict__ pacc, const float* __restrict__ pl,
    const int* __restrict__ clen, float* __restrict__ aw) {
    const int h = blockIdx.x, b = blockIdx.y, lane = threadIdx.x;
    const int cl = clen[b];
    int nch = (cl + 255) >> 8;
    if (nch < 1) nch = 1;
    float acc[8], l[8];
#pragma unroll
    for (int t = 0; t < 8; ++t) { acc[t] = 0.f; l[t] = 0.f; }
    for (int c = 0; c < nch; ++c) {
        const size_t base = (size_t)((c * Bn + b) * Hn + h);
#pragma unroll
        for (int t = 0; t < 8; ++t) acc[t] += pacc[base * 512 + t * 64 + lane];
#pragma unroll
        for (int t = 0; t < 8; ++t) l[t] += pl[base * 8 + t];
    }
#pragma unroll
    for (int t = 0; t < 8; ++t)
        aw[(size_t)(b * Tn + t) * Cn + h * HDn + lane] = acc[t] / l[t];
}

// ---------------- Sum final-GEMM partials + bias ----------------
__global__ __launch_bounds__(256) void bias_out_kernel(
    const float* __restrict__ opart, const float* __restrict__ bo, float* __restrict__ out) {
    const int f4 = blockIdx.x * 256 + threadIdx.x; // 65536 float4s
    const float4 a0 = *(const float4*)(opart + (size_t)f4 * 4);
    const float4 a1 = *(const float4*)(opart + PROJ_PART + (size_t)f4 * 4);
    const float4 a2 = *(const float4*)(opart + 2 * PROJ_PART + (size_t)f4 * 4);
    const float4 a3 = *(const float4*)(opart + 3 * PROJ_PART + (size_t)f4 * 4);
    const float4 bv = *(const float4*)&bo[(f4 & 255) * 4];
    float4 o = make_float4(a0.x + a1.x + a2.x + a3.x + bv.x,
                           a0.y + a1.y + a2.y + a3.y + bv.y,
                           a0.z + a1.z + a2.z + a3.z + bv.z,
                           a0.w + a1.w + a2.w + a3.w + bv.w);
    *(float4*)&out[(size_t)f4 * 4] = o;
}

extern "C" void kernel_launch(void* const* d_in, const int* in_sizes, int n_in,
                              void* d_out, int out_size, void* d_ws, size_t ws_size,
                              hipStream_t stream) {
    const float* x  = (const float*)d_in[0];
    const float* ck = (const float*)d_in[1];
    const float* cv = (const float*)d_in[2];
    const int*   cl = (const int*)d_in[3];
    const float* wq = (const float*)d_in[4];
    const float* wk = (const float*)d_in[5];
    const float* wv = (const float*)d_in[6];
    const float* wo = (const float*)d_in[7];
    const float* bo = (const float*)d_in[8];
    float* out = (float*)d_out;
    float* ws = (float*)d_ws;

    float* qpart = ws + QP_OFF;
    float* kpart = ws + KP_OFF;
    float* vpart = ws + VP_OFF;
    float* pacc  = ws + PACC_OFF;
    float* pl    = ws + PL_OFF;
    float* aw    = ws + AW_OFF;
    float* opart = ws + OP_OFF;
    float* qr    = ws + QR_OFF;
    float* knew  = ws + KN_OFF;
    float* vnew  = ws + VN_OFF;

    // 1) q/k/v projections (K-split-4 partials)
    proj3_kernel<<<dim3(16, 4, 12), dim3(256), 0, stream>>>(x, wq, wk, wv, qpart, kpart, vpart);
    // 1b) reduce partials -> q (pre-scaled), k_new, v_new
    prereduce_kernel<<<dim3(256), dim3(256), 0, stream>>>(qpart, kpart, vpart, qr, knew, vnew);
    // 2) attention partials per (chunk, head, batch)
    attn_kernel<<<dim3(NCHUNK, Hn, Bn), dim3(256), 0, stream>>>(qr, knew, vnew, ck, cv, cl, pacc, pl);
    // 3) merge + normalize
    attn_merge_kernel<<<dim3(Hn, Bn), dim3(64), 0, stream>>>(pacc, pl, cl, aw);
    // 4) output projection (K-split-4 partials)
    gemm1_kernel<<<dim3(16, 4, KSPLIT), dim3(256), 0, stream>>>(aw, wo, opart);
    // 5) sum partials + bias
    bias_out_kernel<<<dim3(256), dim3(256), 0, stream>>>(opart, bo, out);
}

// Round 4
// 332.949 us; speedup vs baseline: 1.3504x; 1.3504x over previous
//
#include <hip/hip_runtime.h>

// Problem constants
constexpr int Bn = 32, Tn = 8, Cn = 1024, Sn = 4096, Hn = 16, HDn = 64;
constexpr int CHUNK = 512, NCHUNK = 8; // keys per attn block
constexpr int KSPLIT = 4;              // K-split for the 256x1024x1024 GEMMs
constexpr float SCALE = 0.125f;        // 1/sqrt(64)

// Workspace layout (in floats)
constexpr size_t PROJ_PART = (size_t)Bn * Tn * Cn;          // 262144
constexpr size_t QP_OFF = 0;
constexpr size_t KP_OFF = QP_OFF + KSPLIT * PROJ_PART;
constexpr size_t VP_OFF = KP_OFF + KSPLIT * PROJ_PART;
constexpr size_t PACC_OFF = VP_OFF + KSPLIT * PROJ_PART;
constexpr size_t PACC_SZ = (size_t)NCHUNK * Bn * Hn * Tn * HDn;
constexpr size_t PL_OFF = PACC_OFF + PACC_SZ;
constexpr size_t PL_SZ = (size_t)NCHUNK * Bn * Hn * Tn;
constexpr size_t AW_OFF = PL_OFF + PL_SZ;
constexpr size_t AW_SZ = PROJ_PART;
constexpr size_t OP_OFF = AW_OFF + AW_SZ;
constexpr size_t OP_SZ = (size_t)KSPLIT * PROJ_PART;
constexpr size_t QR_OFF = OP_OFF + OP_SZ;                   // reduced q (pre-scaled)
constexpr size_t KN_OFF = QR_OFF + PROJ_PART;               // reduced k_new
constexpr size_t VN_OFF = KN_OFF + PROJ_PART;               // reduced v_new

typedef __attribute__((address_space(3))) unsigned int lds_uint;
typedef const __attribute__((address_space(1))) unsigned int glb_uint;

__device__ __forceinline__ void gload_lds16(const float* g, float* l) {
    __builtin_amdgcn_global_load_lds((glb_uint*)g, (lds_uint*)l, 16, 0, 0);
}

// ---------------- GEMM: Y_partial[sigma] = X(256xK-slice) @ W^T ----------------
__device__ __forceinline__ void gemm_body(const float* __restrict__ X,
                                          const float* __restrict__ W,
                                          float* __restrict__ Opart,
                                          int sigma, int jblk, int iblk) {
    __shared__ float wl[64][68]; // [k][j], pad 68
    const int tid = threadIdx.x;
    const int c = tid & 15, a = tid >> 4;
    const int j0 = jblk * 64;
    const int ib = iblk * 64 + a * 4;
    const int k0 = sigma * 256;

    float acc[4][4];
#pragma unroll
    for (int ii = 0; ii < 4; ++ii)
#pragma unroll
        for (int jj = 0; jj < 4; ++jj) acc[ii][jj] = 0.f;

    for (int kt = 0; kt < 4; ++kt) {
        const int k1 = k0 + kt * 64;
#pragma unroll
        for (int stp = 0; stp < 4; ++stp) {
            int f4 = stp * 256 + tid;
            int jr = f4 >> 4, e4 = f4 & 15;
            float4 wv = *(const float4*)&W[(size_t)(j0 + jr) * Cn + k1 + e4 * 4];
            wl[e4 * 4 + 0][jr] = wv.x;
            wl[e4 * 4 + 1][jr] = wv.y;
            wl[e4 * 4 + 2][jr] = wv.z;
            wl[e4 * 4 + 3][jr] = wv.w;
        }
        __syncthreads();
#pragma unroll 4
        for (int k4 = 0; k4 < 16; ++k4) {
            float4 xv[4];
#pragma unroll
            for (int ii = 0; ii < 4; ++ii)
                xv[ii] = *(const float4*)&X[(size_t)(ib + ii) * Cn + k1 + k4 * 4];
#pragma unroll
            for (int kk = 0; kk < 4; ++kk) {
                float4 wv = *(const float4*)&wl[k4 * 4 + kk][c * 4];
#pragma unroll
                for (int ii = 0; ii < 4; ++ii) {
                    const float xs = (kk == 0) ? xv[ii].x : (kk == 1) ? xv[ii].y
                                   : (kk == 2) ? xv[ii].z : xv[ii].w;
                    acc[ii][0] += xs * wv.x;
                    acc[ii][1] += xs * wv.y;
                    acc[ii][2] += xs * wv.z;
                    acc[ii][3] += xs * wv.w;
                }
            }
        }
        __syncthreads();
    }
    float* op = Opart + (size_t)sigma * PROJ_PART;
#pragma unroll
    for (int ii = 0; ii < 4; ++ii) {
        float4 o = make_float4(acc[ii][0], acc[ii][1], acc[ii][2], acc[ii][3]);
        *(float4*)&op[(size_t)(ib + ii) * Cn + j0 + c * 4] = o;
    }
}

__global__ __launch_bounds__(256) void proj3_kernel(
    const float* __restrict__ X, const float* __restrict__ W0,
    const float* __restrict__ W1, const float* __restrict__ W2,
    float* __restrict__ O0, float* __restrict__ O1, float* __restrict__ O2) {
    const int z = blockIdx.z;
    const float* W = (z < 4) ? W0 : (z < 8 ? W1 : W2);
    float* O = (z < 4) ? O0 : (z < 8 ? O1 : O2);
    gemm_body(X, W, O, z & 3, blockIdx.x, blockIdx.y);
}

__global__ __launch_bounds__(256) void gemm1_kernel(
    const float* __restrict__ X, const float* __restrict__ W, float* __restrict__ O) {
    gemm_body(X, W, O, blockIdx.z, blockIdx.x, blockIdx.y);
}

// ---------------- Pre-reduce K-split partials -> q (scaled), k_new, v_new ------
__global__ __launch_bounds__(256) void prereduce_kernel(
    const float* __restrict__ qp, const float* __restrict__ kp,
    const float* __restrict__ vp, float* __restrict__ q,
    float* __restrict__ kn, float* __restrict__ vn) {
    const size_t i = ((size_t)blockIdx.x * 256 + threadIdx.x) * 4;
#define SUM4(P)                                                              \
    make_float4(                                                             \
        (*(const float4*)(P + i)).x + (*(const float4*)(P + PROJ_PART + i)).x + \
        (*(const float4*)(P + 2 * PROJ_PART + i)).x + (*(const float4*)(P + 3 * PROJ_PART + i)).x, \
        (*(const float4*)(P + i)).y + (*(const float4*)(P + PROJ_PART + i)).y + \
        (*(const float4*)(P + 2 * PROJ_PART + i)).y + (*(const float4*)(P + 3 * PROJ_PART + i)).y, \
        (*(const float4*)(P + i)).z + (*(const float4*)(P + PROJ_PART + i)).z + \
        (*(const float4*)(P + 2 * PROJ_PART + i)).z + (*(const float4*)(P + 3 * PROJ_PART + i)).z, \
        (*(const float4*)(P + i)).w + (*(const float4*)(P + PROJ_PART + i)).w + \
        (*(const float4*)(P + 2 * PROJ_PART + i)).w + (*(const float4*)(P + 3 * PROJ_PART + i)).w)
    float4 qv = SUM4(qp);
    qv.x *= SCALE; qv.y *= SCALE; qv.z *= SCALE; qv.w *= SCALE;
    *(float4*)&q[i] = qv;
    *(float4*)&kn[i] = SUM4(kp);
    *(float4*)&vn[i] = SUM4(vp);
#undef SUM4
}

// ---------------- Attention partials: pipelined double-buffered streaming ------
// Grid (cq=8, h=16, b=32), block 256 = 4 waves; block processes 512 keys as
// 8 subtiles of 64 rows. Waves t-split (wave w owns t = 2w, 2w+1) -> per-wave
// complete accumulators. Per subtile: all waves cooperatively gload_lds K
// (source-swizzled slot^=(row&15)) and V (linear); counted vmcnt(8) + raw
// s_barrier pipeline (m201 pattern): loads for subtile st+2 overlap compute st.
__global__ __launch_bounds__(256) void attn_kernel(
    const float* __restrict__ q, const float* __restrict__ kn,
    const float* __restrict__ vn, const float* __restrict__ ck,
    const float* __restrict__ cv, const int* __restrict__ clen,
    float* __restrict__ pacc, float* __restrict__ pl) {
    const int cq = blockIdx.x, h = blockIdx.y, b = blockIdx.z;
    const int cl = clen[b];
    if (cq != 0 && cq * CHUNK >= cl) return; // uniform early exit

    const int tid = threadIdx.x, wave = tid >> 6, lane = tid & 63;
    const int t0 = wave * 2;

    __shared__ float K_l[2][64][64]; // 32 KB, swizzled slots
    __shared__ float V_l[2][64][64]; // 32 KB, linear
    __shared__ float p_l[8][64];     // 2 KB, [t][row]

    // q for this wave's 2 t's -> registers (block-uniform broadcast loads)
    float4 qreg[2][16];
    {
        const float* qb = q + ((size_t)b * Tn + t0) * Cn + (size_t)h * HDn;
#pragma unroll
        for (int tj = 0; tj < 2; ++tj)
#pragma unroll
            for (int dg = 0; dg < 16; ++dg)
                qreg[tj][dg] = *(const float4*)(qb + (size_t)tj * Cn + dg * 4);
    }

    // max(cache_len) (for the zero-pad denominator term)
    int mv = clen[lane & 31];
#pragma unroll
    for (int off = 16; off >= 1; off >>= 1) {
        int o = __shfl_xor(mv, off);
        mv = mv > o ? mv : o;
    }

    const int nvc = min(max(cl - cq * CHUNK, 0), CHUNK);
    const int nst = (nvc + 63) >> 6; // subtiles with any valid rows

    const int row_in = lane >> 4, slot = lane & 15;
    const int rg = lane >> 4, d4 = lane & 15; // PV mapping
    const size_t gb0 = ((size_t)b * Sn + (size_t)cq * CHUNK) * Cn + (size_t)h * HDn;

    float av0[4] = {0.f, 0.f, 0.f, 0.f}, av1[4] = {0.f, 0.f, 0.f, 0.f};
    float lden0 = 0.f, lden1 = 0.f;

    auto issue_tile = [&](int st, int bb) {
        const size_t gb = gb0 + (size_t)st * 64 * Cn;
#pragma unroll
        for (int i = 0; i < 4; ++i) {
            const int row = wave * 16 + i * 4 + row_in;
            const int dgk = slot ^ (row & 15);
            gload_lds16(ck + gb + (size_t)row * Cn + dgk * 4, &K_l[bb][wave * 16 + i * 4][0]);
        }
#pragma unroll
        for (int i = 0; i < 4; ++i) {
            const int row = wave * 16 + i * 4 + row_in;
            gload_lds16(cv + gb + (size_t)row * Cn + slot * 4, &V_l[bb][wave * 16 + i * 4][0]);
        }
    };

    auto compute = [&](int bb, int nv) {
        // QK: lane = row; swizzled 2-way-max b128 reads
        float s0 = 0.f, s1 = 0.f;
        const int swz = lane & 15;
#pragma unroll
        for (int dg = 0; dg < 16; ++dg) {
            const float4 kv = *(const float4*)&K_l[bb][lane][(dg ^ swz) * 4];
            s0 += kv.x * qreg[0][dg].x + kv.y * qreg[0][dg].y +
                  kv.z * qreg[0][dg].z + kv.w * qreg[0][dg].w;
            s1 += kv.x * qreg[1][dg].x + kv.y * qreg[1][dg].y +
                  kv.z * qreg[1][dg].z + kv.w * qreg[1][dg].w;
        }
        const bool val = lane < nv;
        const float pa = val ? __expf(s0) : 0.f;
        const float pb = val ? __expf(s1) : 0.f;
        lden0 += pa;
        lden1 += pb;
        p_l[t0][lane] = pa;      // bank=lane%32, 2-way: free; in-wave RAW below
        p_l[t0 + 1][lane] = pb;
        // PV: lane = (rg: 16-row group, d4: 4-float dim group)
#pragma unroll
        for (int j4 = 0; j4 < 4; ++j4) {
            const int r = rg * 16 + j4 * 4;
            const float4 pA = *(const float4*)&p_l[t0][r];     // broadcast
            const float4 pB = *(const float4*)&p_l[t0 + 1][r]; // broadcast
#pragma unroll
            for (int u = 0; u < 4; ++u) {
                const float4 vv = *(const float4*)&V_l[bb][r + u][d4 * 4];
                const float fa = (u == 0) ? pA.x : (u == 1) ? pA.y : (u == 2) ? pA.z : pA.w;
                const float fb = (u == 0) ? pB.x : (u == 1) ? pB.y : (u == 2) ? pB.z : pB.w;
                av0[0] += fa * vv.x; av0[1] += fa * vv.y; av0[2] += fa * vv.z; av0[3] += fa * vv.w;
                av1[0] += fb * vv.x; av1[1] += fb * vv.y; av1[2] += fb * vv.z; av1[3] += fb * vv.w;
            }
        }
    };

    // prologue: 2 subtiles in flight
    if (nst > 0) issue_tile(0, 0);
    if (nst > 1) issue_tile(1, 1);
    __builtin_amdgcn_sched_barrier(0);

    for (int st = 0; st < nst; ++st) {
        if (st + 1 < nst) {
            asm volatile("s_waitcnt vmcnt(8)" ::: "memory");
        } else {
            asm volatile("s_waitcnt vmcnt(0)" ::: "memory");
        }
        __builtin_amdgcn_sched_barrier(0);
        __builtin_amdgcn_s_barrier(); // subtile st resident for all waves
        compute(st & 1, nvc - st * 64);
        __builtin_amdgcn_s_barrier(); // all waves done reading buf st&1
        __builtin_amdgcn_sched_barrier(0);
        if (st + 2 < nst) {
            issue_tile(st + 2, st & 1);
            __builtin_amdgcn_sched_barrier(0);
        }
    }

    // new keys (8 rows) into buffer 0; only chunk 0 blocks
    if (cq == 0) {
        if (wave == 0) {
            const size_t kb = (size_t)b * Tn * Cn + (size_t)h * HDn;
#pragma unroll
            for (int i = 0; i < 2; ++i) {
                const int row = i * 4 + row_in;
                const int dgk = slot ^ (row & 15);
                gload_lds16(kn + kb + (size_t)row * Cn + dgk * 4, &K_l[0][i * 4][0]);
            }
#pragma unroll
            for (int i = 0; i < 2; ++i) {
                const int row = i * 4 + row_in;
                gload_lds16(vn + kb + (size_t)row * Cn + slot * 4, &V_l[0][i * 4][0]);
            }
        }
        asm volatile("s_waitcnt vmcnt(0)" ::: "memory");
        __builtin_amdgcn_sched_barrier(0);
        __builtin_amdgcn_s_barrier();
        compute(0, Tn); // rows 0..7 valid (always, independent of cl)
    }

    // lden: 64-lane butterfly (rows); then add zero-pad count (chunk 0 only)
#pragma unroll
    for (int off = 32; off >= 1; off >>= 1) {
        lden0 += __shfl_xor(lden0, off);
        lden1 += __shfl_xor(lden1, off);
    }
    if (cq == 0) {
        const float pad = (float)(mv - cl);
        lden0 += pad;
        lden1 += pad;
    }
    // av: reduce over the 4 row-groups (lanes l, l^16, l^32, l^48)
#pragma unroll
    for (int e = 0; e < 4; ++e) {
        av0[e] += __shfl_xor(av0[e], 16);
        av0[e] += __shfl_xor(av0[e], 32);
        av1[e] += __shfl_xor(av1[e], 16);
        av1[e] += __shfl_xor(av1[e], 32);
    }

    const size_t obase = (size_t)((cq * Bn + b) * Hn + h);
    if (lane < 16) {
        *(float4*)&pacc[obase * 512 + (size_t)t0 * 64 + lane * 4] =
            make_float4(av0[0], av0[1], av0[2], av0[3]);
        *(float4*)&pacc[obase * 512 + (size_t)(t0 + 1) * 64 + lane * 4] =
            make_float4(av1[0], av1[1], av1[2], av1[3]);
    }
    if (lane == 0) {
        pl[obase * 8 + t0] = lden0;
        pl[obase * 8 + t0 + 1] = lden1;
    }
}

// ---------------- Merge chunk partials, normalize ----------------
__global__ __launch_bounds__(64) void attn_merge_kernel(
    const float* __restrict__ pacc, const float* __restrict__ pl,
    const int* __restrict__ clen, float* __restrict__ aw) {
    const int h = blockIdx.x, b = blockIdx.y, lane = threadIdx.x;
    const int cl = clen[b];
    int nch = (cl + CHUNK - 1) / CHUNK;
    if (nch < 1) nch = 1;
    float acc[8], l[8];
#pragma unroll
    for (int t = 0; t < 8; ++t) { acc[t] = 0.f; l[t] = 0.f; }
    for (int c = 0; c < nch; ++c) {
        const size_t base = (size_t)((c * Bn + b) * Hn + h);
#pragma unroll
        for (int t = 0; t < 8; ++t) acc[t] += pacc[base * 512 + t * 64 + lane];
#pragma unroll
        for (int t = 0; t < 8; ++t) l[t] += pl[base * 8 + t];
    }
#pragma unroll
    for (int t = 0; t < 8; ++t)
        aw[(size_t)(b * Tn + t) * Cn + h * HDn + lane] = acc[t] / l[t];
}

// ---------------- Sum final-GEMM partials + bias ----------------
__global__ __launch_bounds__(256) void bias_out_kernel(
    const float* __restrict__ opart, const float* __restrict__ bo, float* __restrict__ out) {
    const int f4 = blockIdx.x * 256 + threadIdx.x; // 65536 float4s
    const float4 a0 = *(const float4*)(opart + (size_t)f4 * 4);
    const float4 a1 = *(const float4*)(opart + PROJ_PART + (size_t)f4 * 4);
    const float4 a2 = *(const float4*)(opart + 2 * PROJ_PART + (size_t)f4 * 4);
    const float4 a3 = *(const float4*)(opart + 3 * PROJ_PART + (size_t)f4 * 4);
    const float4 bv = *(const float4*)&bo[(f4 & 255) * 4];
    float4 o = make_float4(a0.x + a1.x + a2.x + a3.x + bv.x,
                           a0.y + a1.y + a2.y + a3.y + bv.y,
                           a0.z + a1.z + a2.z + a3.z + bv.z,
                           a0.w + a1.w + a2.w + a3.w + bv.w);
    *(float4*)&out[(size_t)f4 * 4] = o;
}

extern "C" void kernel_launch(void* const* d_in, const int* in_sizes, int n_in,
                              void* d_out, int out_size, void* d_ws, size_t ws_size,
                              hipStream_t stream) {
    const float* x  = (const float*)d_in[0];
    const float* ck = (const float*)d_in[1];
    const float* cv = (const float*)d_in[2];
    const int*   cl = (const int*)d_in[3];
    const float* wq = (const float*)d_in[4];
    const float* wk = (const float*)d_in[5];
    const float* wv = (const float*)d_in[6];
    const float* wo = (const float*)d_in[7];
    const float* bo = (const float*)d_in[8];
    float* out = (float*)d_out;
    float* ws = (float*)d_ws;

    float* qpart = ws + QP_OFF;
    float* kpart = ws + KP_OFF;
    float* vpart = ws + VP_OFF;
    float* pacc  = ws + PACC_OFF;
    float* pl    = ws + PL_OFF;
    float* aw    = ws + AW_OFF;
    float* opart = ws + OP_OFF;
    float* qr    = ws + QR_OFF;
    float* knew  = ws + KN_OFF;
    float* vnew  = ws + VN_OFF;

    // 1) q/k/v projections (K-split-4 partials)
    proj3_kernel<<<dim3(16, 4, 12), dim3(256), 0, stream>>>(x, wq, wk, wv, qpart, kpart, vpart);
    // 1b) reduce partials -> q (pre-scaled), k_new, v_new
    prereduce_kernel<<<dim3(256), dim3(256), 0, stream>>>(qpart, kpart, vpart, qr, knew, vnew);
    // 2) attention partials per (chunk, head, batch) — pipelined streaming
    attn_kernel<<<dim3(NCHUNK, Hn, Bn), dim3(256), 0, stream>>>(qr, knew, vnew, ck, cv, cl, pacc, pl);
    // 3) merge + normalize
    attn_merge_kernel<<<dim3(Hn, Bn), dim3(64), 0, stream>>>(pacc, pl, cl, aw);
    // 4) output projection (K-split-4 partials)
    gemm1_kernel<<<dim3(16, 4, KSPLIT), dim3(256), 0, stream>>>(aw, wo, opart);
    // 5) sum partials + bias
    bias_out_kernel<<<dim3(256), dim3(256), 0, stream>>>(opart, bo, out);
}